// Round 1
// baseline (893.159 us; speedup 1.0000x reference)
//
#include <hip/hip_runtime.h>
#include <hip/hip_bf16.h>

#define B_TOK 4096
#define DIM   2048
#define HID   4096
#define NEXP  8
#define CAP   4224   /* 4096 + BM slack for padding */

#define BM 128
#define BN 128
#define BK 64
#define LSTRIDE 72   /* bf16 elems per LDS row = BK + 8 pad; 144 B, 16B-aligned */

typedef short  bf16x8 __attribute__((ext_vector_type(8)));
typedef unsigned short us16x8 __attribute__((ext_vector_type(8)));
typedef float  f32x4  __attribute__((ext_vector_type(4)));

__device__ __forceinline__ unsigned short f2bf(float f) {
    unsigned u = __builtin_bit_cast(unsigned, f);
    u += 0x7fffu + ((u >> 16) & 1u);          // round-to-nearest-even
    return (unsigned short)(u >> 16);
}

// ---------------------------------------------------------------------------
// c[n][e] = dot(emb[n], gate_W[e][D:2D]) + gate_b[e]   (24 waves total)
// ---------------------------------------------------------------------------
__global__ __launch_bounds__(256) void compute_c_kernel(
    const float* __restrict__ emb, const float* __restrict__ gate_W,
    const float* __restrict__ gate_b, float* __restrict__ cbuf) {
    int wave = (blockIdx.x * blockDim.x + threadIdx.x) >> 6;
    int lane = threadIdx.x & 63;
    if (wave >= 24) return;
    int n = wave >> 3, e = wave & 7;
    const float4* er = (const float4*)(emb + (size_t)n * DIM);
    const float4* wr = (const float4*)(gate_W + (size_t)e * 2 * DIM + DIM);
    float acc = 0.f;
    for (int c = lane; c < DIM / 4; c += 64) {
        float4 a = er[c], b = wr[c];
        acc += a.x * b.x + a.y * b.y + a.z * b.z + a.w * b.w;
    }
    #pragma unroll
    for (int off = 32; off; off >>= 1) acc += __shfl_down(acc, off, 64);
    if (lane == 0) cbuf[n * 8 + e] = acc + gate_b[e];
}

// ---------------------------------------------------------------------------
// Gating: one wave per token. fp32 logits, top-2 (jax tie-break: lower idx),
// softmax over 2, scatter into per-expert lists, write topk_idx as floats.
// ---------------------------------------------------------------------------
__global__ __launch_bounds__(256) void gating_kernel(
    const float* __restrict__ x, const int* __restrict__ labels,
    const float* __restrict__ gate_W, const float* __restrict__ cbuf,
    int* __restrict__ counts, int* __restrict__ tlist,
    float* __restrict__ wlist, float* __restrict__ out_idx) {
    int wave = threadIdx.x >> 6, lane = threadIdx.x & 63;
    int b = blockIdx.x * 4 + wave;
    const float4* xr  = (const float4*)(x + (size_t)b * DIM);
    const float4* gw4 = (const float4*)gate_W;
    float acc[8] = {0.f, 0.f, 0.f, 0.f, 0.f, 0.f, 0.f, 0.f};
    for (int c = lane; c < DIM / 4; c += 64) {
        float4 xv = xr[c];
        #pragma unroll
        for (int e = 0; e < 8; ++e) {
            float4 wv = gw4[e * (2 * DIM / 4) + c];
            acc[e] += xv.x * wv.x + xv.y * wv.y + xv.z * wv.z + xv.w * wv.w;
        }
    }
    #pragma unroll
    for (int off = 32; off; off >>= 1) {
        #pragma unroll
        for (int e = 0; e < 8; ++e) acc[e] += __shfl_down(acc[e], off, 64);
    }
    if (lane == 0) {
        int lbl = labels[b];
        float lg[8];
        #pragma unroll
        for (int e = 0; e < 8; ++e) lg[e] = acc[e] + cbuf[lbl * 8 + e];
        int e0 = 0; float t0 = lg[0];
        #pragma unroll
        for (int e = 1; e < 8; ++e) if (lg[e] > t0) { t0 = lg[e]; e0 = e; }
        int e1 = -1; float t1 = -1e30f;
        #pragma unroll
        for (int e = 0; e < 8; ++e)
            if (e != e0 && lg[e] > t1) { t1 = lg[e]; e1 = e; }
        float w0 = 1.f / (1.f + expf(t1 - t0));   // == softmax([t0,t1])[0]
        float w1 = 1.f - w0;
        int p0 = atomicAdd(&counts[e0], 1);
        tlist[e0 * CAP + p0] = b; wlist[e0 * CAP + p0] = w0;
        int p1 = atomicAdd(&counts[e1], 1);
        tlist[e1 * CAP + p1] = b; wlist[e1 * CAP + p1] = w1;
        out_idx[2 * b]     = (float)e0;
        out_idx[2 * b + 1] = (float)e1;
    }
}

// ---------------------------------------------------------------------------
// Pad each expert list to a multiple of BM with (token 0, weight 0).
// ---------------------------------------------------------------------------
__global__ void pad_kernel(const int* __restrict__ counts,
                           int* __restrict__ tlist, float* __restrict__ wlist) {
    int e = blockIdx.x, c = counts[e];
    int padded = (c + BM - 1) & ~(BM - 1);
    int i = c + threadIdx.x;
    if (i < padded) { tlist[e * CAP + i] = 0; wlist[e * CAP + i] = 0.f; }
}

// ---------------------------------------------------------------------------
// Grouped expert GEMM: per (expert, 128-token tile, 128-col tile).
// bf16 MFMA 16x16x32, fp32->bf16 conversion during LDS staging.
// ---------------------------------------------------------------------------
__global__ __launch_bounds__(256) void moe_gemm_kernel(
    const float* __restrict__ x, const float* __restrict__ expert_W,
    const float* __restrict__ expert_b, const int* __restrict__ counts,
    const int* __restrict__ tlist, const float* __restrict__ wlist,
    float* __restrict__ out) {
    const int e  = blockIdx.z;
    const int m0 = blockIdx.y * BM;
    if (m0 >= counts[e]) return;            // beyond this expert's tokens
    const int n0 = blockIdx.x * BN;

    __shared__ unsigned short As[BM][LSTRIDE];
    __shared__ unsigned short Bs[BN][LSTRIDE];
    __shared__ int   toks[BM];
    __shared__ float wts[BM];

    const int t = threadIdx.x;
    if (t < BM) {
        toks[t] = tlist[e * CAP + m0 + t];
        wts[t]  = wlist[e * CAP + m0 + t];
    }
    __syncthreads();

    const int lane = t & 63, wave = t >> 6;
    const int wm = wave >> 1, wn = wave & 1;
    const int r = lane & 15, quad = lane >> 4;
    const float* Wbase = expert_W + (size_t)e * HID * DIM;

    f32x4 acc[4][4] = {};

    const int srow = t >> 3;          // 0..31
    const int scol = (t & 7) * 8;     // 0,8,...,56

    for (int k0 = 0; k0 < DIM; k0 += BK) {
        #pragma unroll
        for (int rr = 0; rr < 4; ++rr) {      // A tile: gathered token rows
            int row = srow + rr * 32;
            const float* src = x + (size_t)toks[row] * DIM + k0 + scol;
            float4 v0 = *(const float4*)src;
            float4 v1 = *(const float4*)(src + 4);
            us16x8 o = { f2bf(v0.x), f2bf(v0.y), f2bf(v0.z), f2bf(v0.w),
                         f2bf(v1.x), f2bf(v1.y), f2bf(v1.z), f2bf(v1.w) };
            *(us16x8*)&As[row][scol] = o;
        }
        #pragma unroll
        for (int rr = 0; rr < 4; ++rr) {      // B tile: W[e] rows (B^T form)
            int row = srow + rr * 32;
            const float* src = Wbase + (size_t)(n0 + row) * DIM + k0 + scol;
            float4 v0 = *(const float4*)src;
            float4 v1 = *(const float4*)(src + 4);
            us16x8 o = { f2bf(v0.x), f2bf(v0.y), f2bf(v0.z), f2bf(v0.w),
                         f2bf(v1.x), f2bf(v1.y), f2bf(v1.z), f2bf(v1.w) };
            *(us16x8*)&Bs[row][scol] = o;
        }
        __syncthreads();
        #pragma unroll
        for (int kk = 0; kk < 2; ++kk) {
            bf16x8 af[4], bfr[4];
            #pragma unroll
            for (int i = 0; i < 4; ++i) {
                af[i]  = *(const bf16x8*)&As[wm * 64 + i * 16 + r][kk * 32 + quad * 8];
                bfr[i] = *(const bf16x8*)&Bs[wn * 64 + i * 16 + r][kk * 32 + quad * 8];
            }
            #pragma unroll
            for (int im = 0; im < 4; ++im)
                #pragma unroll
                for (int in = 0; in < 4; ++in)
                    acc[im][in] = __builtin_amdgcn_mfma_f32_16x16x32_bf16(
                        af[im], bfr[in], acc[im][in], 0, 0, 0);
        }
        __syncthreads();
    }

    // Epilogue: out[tok] += w * (acc + bias).  C/D: col=lane&15, row=4*quad+reg.
    const float* eb = expert_b + (size_t)e * HID;
    #pragma unroll
    for (int in = 0; in < 4; ++in) {
        int col = n0 + wn * 64 + in * 16 + r;
        float bias = eb[col];
        #pragma unroll
        for (int im = 0; im < 4; ++im) {
            int rowb = wm * 64 + im * 16 + quad * 4;
            #pragma unroll
            for (int r4 = 0; r4 < 4; ++r4) {
                int row = rowb + r4;
                float w = wts[row];
                if (w != 0.f)
                    atomicAdd(out + (size_t)toks[row] * HID + col,
                              w * (acc[im][in][r4] + bias));
            }
        }
    }
}

// ---------------------------------------------------------------------------
extern "C" void kernel_launch(void* const* d_in, const int* in_sizes, int n_in,
                              void* d_out, int out_size, void* d_ws, size_t ws_size,
                              hipStream_t stream) {
    const float* x        = (const float*)d_in[0];
    const int*   labels   = (const int*)  d_in[1];
    const float* emb      = (const float*)d_in[2];
    const float* gate_W   = (const float*)d_in[3];
    const float* gate_b   = (const float*)d_in[4];
    const float* expert_W = (const float*)d_in[5];
    const float* expert_b = (const float*)d_in[6];
    float* out = (float*)d_out;

    char* ws = (char*)d_ws;
    int*   counts = (int*)ws;                                  // 32 B
    float* cbuf   = (float*)(ws + 128);                        // 96 B
    int*   tlist  = (int*)(ws + 512);                          // 8*4224*4
    float* wlist  = (float*)(ws + 512 + NEXP * CAP * 4);       // 8*4224*4

    hipMemsetAsync(counts, 0, 8 * sizeof(int), stream);
    hipMemsetAsync(out, 0, (size_t)B_TOK * HID * sizeof(float), stream);

    compute_c_kernel<<<6, 256, 0, stream>>>(emb, gate_W, gate_b, cbuf);
    gating_kernel<<<B_TOK / 4, 256, 0, stream>>>(
        x, labels, gate_W, cbuf, counts, tlist, wlist,
        out + (size_t)B_TOK * HID);
    pad_kernel<<<NEXP, BM, 0, stream>>>(counts, tlist, wlist);
    moe_gemm_kernel<<<dim3(HID / BN, B_TOK / BM, NEXP), 256, 0, stream>>>(
        x, expert_W, expert_b, counts, tlist, wlist, out);
}

// Round 2
// 891.474 us; speedup vs baseline: 1.0019x; 1.0019x over previous
//
#include <hip/hip_runtime.h>
#include <hip/hip_bf16.h>

#define B_TOK 4096
#define DIM   2048
#define HID   4096
#define NEXP  8
#define CAP   4224   /* 4096 + BM slack for padding */

#define BM 128
#define BN 128
#define BK 64        /* bf16 elements per K step */

typedef short  bf16x8 __attribute__((ext_vector_type(8)));
typedef unsigned short us16x8 __attribute__((ext_vector_type(8)));
typedef float  f32x4  __attribute__((ext_vector_type(4)));

__device__ __forceinline__ unsigned short f2bf(float f) {
    unsigned u = __builtin_bit_cast(unsigned, f);
    u += 0x7fffu + ((u >> 16) & 1u);          // round-to-nearest-even
    return (unsigned short)(u >> 16);
}

// async global -> LDS, 16 B per lane, LDS dest = wave-uniform base + lane*16
__device__ __forceinline__ void async_copy16(const void* g, void* l) {
    __builtin_amdgcn_global_load_lds(
        (const __attribute__((address_space(1))) unsigned*)g,
        (__attribute__((address_space(3))) unsigned*)l, 16, 0, 0);
}

// ---------------------------------------------------------------------------
// fp32 -> bf16 stream cast, 8 elems / thread (32 B in, 16 B out)
// ---------------------------------------------------------------------------
__global__ __launch_bounds__(256) void cvt_kernel(
    const float* __restrict__ src, unsigned short* __restrict__ dst, long n) {
    long i = ((long)blockIdx.x * 256 + threadIdx.x) * 8;
    if (i >= n) return;
    float4 v0 = *(const float4*)(src + i);
    float4 v1 = *(const float4*)(src + i + 4);
    us16x8 o = { f2bf(v0.x), f2bf(v0.y), f2bf(v0.z), f2bf(v0.w),
                 f2bf(v1.x), f2bf(v1.y), f2bf(v1.z), f2bf(v1.w) };
    *(us16x8*)(dst + i) = o;
}

// ---------------------------------------------------------------------------
// c[n][e] = dot(emb[n], gate_W[e][D:2D]) + gate_b[e]   (24 waves total)
// ---------------------------------------------------------------------------
__global__ __launch_bounds__(256) void compute_c_kernel(
    const float* __restrict__ emb, const float* __restrict__ gate_W,
    const float* __restrict__ gate_b, float* __restrict__ cbuf) {
    int wave = (blockIdx.x * blockDim.x + threadIdx.x) >> 6;
    int lane = threadIdx.x & 63;
    if (wave >= 24) return;
    int n = wave >> 3, e = wave & 7;
    const float4* er = (const float4*)(emb + (size_t)n * DIM);
    const float4* wr = (const float4*)(gate_W + (size_t)e * 2 * DIM + DIM);
    float acc = 0.f;
    for (int c = lane; c < DIM / 4; c += 64) {
        float4 a = er[c], b = wr[c];
        acc += a.x * b.x + a.y * b.y + a.z * b.z + a.w * b.w;
    }
    #pragma unroll
    for (int off = 32; off; off >>= 1) acc += __shfl_down(acc, off, 64);
    if (lane == 0) cbuf[n * 8 + e] = acc + gate_b[e];
}

// ---------------------------------------------------------------------------
// Gating: one wave per token, fp32 (topk_idx must be exact). Top-2 with
// jax tie-break (lower index wins), softmax over 2, scatter to expert lists.
// ---------------------------------------------------------------------------
__global__ __launch_bounds__(256) void gating_kernel(
    const float* __restrict__ x, const int* __restrict__ labels,
    const float* __restrict__ gate_W, const float* __restrict__ cbuf,
    int* __restrict__ counts, int* __restrict__ tlist,
    float* __restrict__ wlist, float* __restrict__ out_idx) {
    int wave = threadIdx.x >> 6, lane = threadIdx.x & 63;
    int b = blockIdx.x * 4 + wave;
    const float4* xr  = (const float4*)(x + (size_t)b * DIM);
    const float4* gw4 = (const float4*)gate_W;
    float acc[8] = {0.f, 0.f, 0.f, 0.f, 0.f, 0.f, 0.f, 0.f};
    for (int c = lane; c < DIM / 4; c += 64) {
        float4 xv = xr[c];
        #pragma unroll
        for (int e = 0; e < 8; ++e) {
            float4 wv = gw4[e * (2 * DIM / 4) + c];
            acc[e] += xv.x * wv.x + xv.y * wv.y + xv.z * wv.z + xv.w * wv.w;
        }
    }
    #pragma unroll
    for (int off = 32; off; off >>= 1) {
        #pragma unroll
        for (int e = 0; e < 8; ++e) acc[e] += __shfl_down(acc[e], off, 64);
    }
    if (lane == 0) {
        int lbl = labels[b];
        float lg[8];
        #pragma unroll
        for (int e = 0; e < 8; ++e) lg[e] = acc[e] + cbuf[lbl * 8 + e];
        int e0 = 0; float t0 = lg[0];
        #pragma unroll
        for (int e = 1; e < 8; ++e) if (lg[e] > t0) { t0 = lg[e]; e0 = e; }
        int e1 = -1; float t1 = -1e30f;
        #pragma unroll
        for (int e = 0; e < 8; ++e)
            if (e != e0 && lg[e] > t1) { t1 = lg[e]; e1 = e; }
        float w0 = 1.f / (1.f + __expf(t1 - t0));
        float w1 = 1.f - w0;
        int p0 = atomicAdd(&counts[e0], 1);
        int p1 = atomicAdd(&counts[e1], 1);
        tlist[e0 * CAP + p0] = b; wlist[e0 * CAP + p0] = w0;
        tlist[e1 * CAP + p1] = b; wlist[e1 * CAP + p1] = w1;
        out_idx[2 * b]     = (float)e0;
        out_idx[2 * b + 1] = (float)e1;
    }
}

// ---------------------------------------------------------------------------
// Pad each expert list to a multiple of BM with (token 0, weight 0).
// ---------------------------------------------------------------------------
__global__ void pad_kernel(const int* __restrict__ counts,
                           int* __restrict__ tlist, float* __restrict__ wlist) {
    int e = blockIdx.x, c = counts[e];
    int padded = (c + BM - 1) & ~(BM - 1);
    int i = c + threadIdx.x;
    if (i < padded) { tlist[e * CAP + i] = 0; wlist[e * CAP + i] = 0.f; }
}

// ---------------------------------------------------------------------------
// Grouped expert GEMM, m97 structure: global_load_lds width-16 staging of
// bf16 tiles, contiguous LDS [128][64] (required by global_load_lds), XOR
// swizzle of K-groups on the GLOBAL side so ds_read_b128 is conflict-free.
// ---------------------------------------------------------------------------
__global__ __launch_bounds__(256) void moe_gemm_kernel(
    const unsigned short* __restrict__ xb, const unsigned short* __restrict__ Wb,
    const float* __restrict__ expert_b, const int* __restrict__ counts,
    const int* __restrict__ tlist, const float* __restrict__ wlist,
    float* __restrict__ out) {
    const int e  = blockIdx.z;
    const int m0 = blockIdx.y * BM;
    if (m0 >= counts[e]) return;            // beyond this expert's tokens
    const int n0 = blockIdx.x * BN;

    __shared__ unsigned short As[BM * BK];  // 16 KB
    __shared__ unsigned short Bs[BN * BK];  // 16 KB
    __shared__ int   toks[BM];
    __shared__ float wts[BM];

    const int t = threadIdx.x;
    if (t < BM) {
        toks[t] = tlist[e * CAP + m0 + t];
        wts[t]  = wlist[e * CAP + m0 + t];
    }
    __syncthreads();

    const int lane = t & 63, wave = t >> 6;
    const int rowc = lane >> 3;                    // row within 8-row chunk
    const int gsw  = ((lane & 7) ^ rowc) * 8;      // swizzled K-group (elems)

    // per-lane global pointers + wave-uniform LDS bases for the 4 chunks
    const unsigned short* gA[4];
    const unsigned short* gB[4];
    unsigned short* ldsA[4];
    unsigned short* ldsB[4];
    #pragma unroll
    for (int j = 0; j < 4; ++j) {
        int row = wave * 32 + j * 8 + rowc;
        gA[j] = xb + (size_t)toks[row] * DIM + gsw;
        gB[j] = Wb + ((size_t)e * HID + n0 + row) * DIM + gsw;
        ldsA[j] = As + (wave * 32 + j * 8) * BK;
        ldsB[j] = Bs + (wave * 32 + j * 8) * BK;
    }

    const int wm = wave >> 1, wn = wave & 1;
    const int r = lane & 15, quad = lane >> 4;

    f32x4 acc[4][4] = {};

    for (int k0 = 0; k0 < DIM; k0 += BK) {
        #pragma unroll
        for (int j = 0; j < 4; ++j) async_copy16(gA[j] + k0, ldsA[j]);
        #pragma unroll
        for (int j = 0; j < 4; ++j) async_copy16(gB[j] + k0, ldsB[j]);
        __syncthreads();    // compiler drains vmcnt before s_barrier
        #pragma unroll
        for (int kk = 0; kk < 2; ++kk) {
            bf16x8 af[4], bfr[4];
            const int pg = ((kk * 4 + quad) ^ (r & 7)) * 8;  // physical group
            #pragma unroll
            for (int i = 0; i < 4; ++i) {
                af[i]  = *(const bf16x8*)&As[(wm * 64 + i * 16 + r) * BK + pg];
                bfr[i] = *(const bf16x8*)&Bs[(wn * 64 + i * 16 + r) * BK + pg];
            }
            #pragma unroll
            for (int im = 0; im < 4; ++im)
                #pragma unroll
                for (int in = 0; in < 4; ++in)
                    acc[im][in] = __builtin_amdgcn_mfma_f32_16x16x32_bf16(
                        af[im], bfr[in], acc[im][in], 0, 0, 0);
        }
        __syncthreads();
    }

    // Epilogue: out[tok] += w * (acc + bias).  C/D: col=lane&15, row=4*quad+reg.
    const float* eb = expert_b + (size_t)e * HID;
    #pragma unroll
    for (int in = 0; in < 4; ++in) {
        int col = n0 + wn * 64 + in * 16 + r;
        float bias = eb[col];
        #pragma unroll
        for (int im = 0; im < 4; ++im) {
            int rowb = wm * 64 + im * 16 + quad * 4;
            #pragma unroll
            for (int r4 = 0; r4 < 4; ++r4) {
                int row = rowb + r4;
                float w = wts[row];
                if (w != 0.f)
                    atomicAdd(out + (size_t)toks[row] * HID + col,
                              w * (acc[im][in][r4] + bias));
            }
        }
    }
}

// ---------------------------------------------------------------------------
extern "C" void kernel_launch(void* const* d_in, const int* in_sizes, int n_in,
                              void* d_out, int out_size, void* d_ws, size_t ws_size,
                              hipStream_t stream) {
    const float* x        = (const float*)d_in[0];
    const int*   labels   = (const int*)  d_in[1];
    const float* emb      = (const float*)d_in[2];
    const float* gate_W   = (const float*)d_in[3];
    const float* gate_b   = (const float*)d_in[4];
    const float* expert_W = (const float*)d_in[5];
    const float* expert_b = (const float*)d_in[6];
    float* out = (float*)d_out;

    char* ws = (char*)d_ws;
    int*   counts = (int*)ws;                                  // 32 B
    float* cbuf   = (float*)(ws + 128);                        // 96 B
    int*   tlist  = (int*)(ws + 512);                          // 8*4224*4
    float* wlist  = (float*)(ws + 512 + NEXP * CAP * 4);       // 8*4224*4
    unsigned short* xb = (unsigned short*)(ws + 512 + 2 * NEXP * CAP * 4);
    unsigned short* Wb = xb + (size_t)B_TOK * DIM;             // +16.8 MB
    // total ws use: ~0.3 MB lists + 16.8 MB xb + 134.2 MB Wb ≈ 151.3 MB

    hipMemsetAsync(counts, 0, 8 * sizeof(int), stream);
    hipMemsetAsync(out, 0, (size_t)B_TOK * HID * sizeof(float), stream);

    cvt_kernel<<<(B_TOK * DIM) / (8 * 256), 256, 0, stream>>>(
        x, xb, (long)B_TOK * DIM);
    cvt_kernel<<<(NEXP * HID * DIM) / (8 * 256), 256, 0, stream>>>(
        expert_W, Wb, (long)NEXP * HID * DIM);
    compute_c_kernel<<<6, 256, 0, stream>>>(emb, gate_W, gate_b, cbuf);
    gating_kernel<<<B_TOK / 4, 256, 0, stream>>>(
        x, labels, gate_W, cbuf, counts, tlist, wlist,
        out + (size_t)B_TOK * HID);
    pad_kernel<<<NEXP, BM, 0, stream>>>(counts, tlist, wlist);
    moe_gemm_kernel<<<dim3(HID / BN, B_TOK / BM, NEXP), 256, 0, stream>>>(
        xb, Wb, expert_b, counts, tlist, wlist, out);
}

// Round 3
// 751.300 us; speedup vs baseline: 1.1888x; 1.1866x over previous
//
#include <hip/hip_runtime.h>
#include <hip/hip_bf16.h>

#define B_TOK 4096
#define DIM   2048
#define HID   4096
#define NEXP  8
#define CAP   4224   /* 4096 + BM slack for padding */

#define BM 128
#define BN 128
#define BK 32        /* bf16 elements per K stage (dbuf: 2 stages in LDS) */
#define KITER (DIM / BK)

typedef short  bf16x8 __attribute__((ext_vector_type(8)));
typedef unsigned short us16x8 __attribute__((ext_vector_type(8)));
typedef float  f32x4  __attribute__((ext_vector_type(4)));

__device__ __forceinline__ unsigned short f2bf(float f) {
    unsigned u = __builtin_bit_cast(unsigned, f);
    u += 0x7fffu + ((u >> 16) & 1u);          // round-to-nearest-even
    return (unsigned short)(u >> 16);
}

// async global -> LDS, 16 B per lane, LDS dest = wave-uniform base + lane*16
__device__ __forceinline__ void async_copy16(const void* g, void* l) {
    __builtin_amdgcn_global_load_lds(
        (const __attribute__((address_space(1))) unsigned*)g,
        (__attribute__((address_space(3))) unsigned*)l, 16, 0, 0);
}

// ---------------------------------------------------------------------------
// fp32 -> bf16 stream cast, 8 elems / thread
// ---------------------------------------------------------------------------
__global__ __launch_bounds__(256) void cvt_kernel(
    const float* __restrict__ src, unsigned short* __restrict__ dst, long n) {
    long i = ((long)blockIdx.x * 256 + threadIdx.x) * 8;
    if (i >= n) return;
    float4 v0 = *(const float4*)(src + i);
    float4 v1 = *(const float4*)(src + i + 4);
    us16x8 o = { f2bf(v0.x), f2bf(v0.y), f2bf(v0.z), f2bf(v0.w),
                 f2bf(v1.x), f2bf(v1.y), f2bf(v1.z), f2bf(v1.w) };
    *(us16x8*)(dst + i) = o;
}

// ---------------------------------------------------------------------------
// c[n][e] = dot(emb[n], gate_W[e][D:2D]) + gate_b[e]   (24 waves total)
// ---------------------------------------------------------------------------
__global__ __launch_bounds__(256) void compute_c_kernel(
    const float* __restrict__ emb, const float* __restrict__ gate_W,
    const float* __restrict__ gate_b, float* __restrict__ cbuf) {
    int wave = (blockIdx.x * blockDim.x + threadIdx.x) >> 6;
    int lane = threadIdx.x & 63;
    if (wave >= 24) return;
    int n = wave >> 3, e = wave & 7;
    const float4* er = (const float4*)(emb + (size_t)n * DIM);
    const float4* wr = (const float4*)(gate_W + (size_t)e * 2 * DIM + DIM);
    float acc = 0.f;
    for (int c = lane; c < DIM / 4; c += 64) {
        float4 a = er[c], b = wr[c];
        acc += a.x * b.x + a.y * b.y + a.z * b.z + a.w * b.w;
    }
    #pragma unroll
    for (int off = 32; off; off >>= 1) acc += __shfl_down(acc, off, 64);
    if (lane == 0) cbuf[n * 8 + e] = acc + gate_b[e];
}

// ---------------------------------------------------------------------------
// Gating: one wave per token, fp32 (topk_idx must be exact). Writes expert
// dispatch lists with rank (0 = top-1 slot, 1 = top-2 slot) and per-token
// combine metadata for the final combine kernel.
// ---------------------------------------------------------------------------
__global__ __launch_bounds__(256) void gating_kernel(
    const float* __restrict__ x, const int* __restrict__ labels,
    const float* __restrict__ gate_W, const float* __restrict__ cbuf,
    int* __restrict__ counts, int* __restrict__ tlist, int* __restrict__ rlist,
    float* __restrict__ wA, float* __restrict__ wB,
    int* __restrict__ eA, int* __restrict__ eB,
    float* __restrict__ out_idx) {
    int wave = threadIdx.x >> 6, lane = threadIdx.x & 63;
    int b = blockIdx.x * 4 + wave;
    const float4* xr  = (const float4*)(x + (size_t)b * DIM);
    const float4* gw4 = (const float4*)gate_W;
    float acc[8] = {0.f, 0.f, 0.f, 0.f, 0.f, 0.f, 0.f, 0.f};
    for (int c = lane; c < DIM / 4; c += 64) {
        float4 xv = xr[c];
        #pragma unroll
        for (int e = 0; e < 8; ++e) {
            float4 wv = gw4[e * (2 * DIM / 4) + c];
            acc[e] += xv.x * wv.x + xv.y * wv.y + xv.z * wv.z + xv.w * wv.w;
        }
    }
    #pragma unroll
    for (int off = 32; off; off >>= 1) {
        #pragma unroll
        for (int e = 0; e < 8; ++e) acc[e] += __shfl_down(acc[e], off, 64);
    }
    if (lane == 0) {
        int lbl = labels[b];
        float lg[8];
        #pragma unroll
        for (int e = 0; e < 8; ++e) lg[e] = acc[e] + cbuf[lbl * 8 + e];
        int e0 = 0; float t0 = lg[0];
        #pragma unroll
        for (int e = 1; e < 8; ++e) if (lg[e] > t0) { t0 = lg[e]; e0 = e; }
        int e1 = -1; float t1 = -1e30f;
        #pragma unroll
        for (int e = 0; e < 8; ++e)
            if (e != e0 && lg[e] > t1) { t1 = lg[e]; e1 = e; }
        float w0 = 1.f / (1.f + __expf(t1 - t0));
        float w1 = 1.f - w0;
        int p0 = atomicAdd(&counts[e0], 1);
        int p1 = atomicAdd(&counts[e1], 1);
        tlist[e0 * CAP + p0] = b; rlist[e0 * CAP + p0] = 0;
        tlist[e1 * CAP + p1] = b; rlist[e1 * CAP + p1] = 1;
        wA[b] = w0; wB[b] = w1; eA[b] = e0; eB[b] = e1;
        out_idx[2 * b]     = (float)e0;
        out_idx[2 * b + 1] = (float)e1;
    }
}

// ---------------------------------------------------------------------------
// Pad each expert list to a multiple of BM: token 0, rank 2 (-> trash row).
// ---------------------------------------------------------------------------
__global__ void pad_kernel(const int* __restrict__ counts,
                           int* __restrict__ tlist, int* __restrict__ rlist) {
    int e = blockIdx.x, c = counts[e];
    int padded = (c + BM - 1) & ~(BM - 1);
    int i = c + threadIdx.x;
    if (i < padded) { tlist[e * CAP + i] = 0; rlist[e * CAP + i] = 2; }
}

// ---------------------------------------------------------------------------
// Grouped expert GEMM. Distance-1 double-buffered global_load_lds (BK=32
// stages, statically distinct LDS buffers so the compiler's vmcnt drain at
// the barrier lands AFTER the compute phase). Epilogue: plain stores —
// rank-0 rows -> d_out, rank-1 rows -> y1 buffer, pad rows -> trash.
// ---------------------------------------------------------------------------
__global__ __launch_bounds__(256, 3) void moe_gemm_kernel(
    const unsigned short* __restrict__ xb, const unsigned short* __restrict__ Wb,
    const int* __restrict__ counts, const int* __restrict__ tlist,
    const int* __restrict__ rlist,
    float* __restrict__ out0, float* __restrict__ y1, float* __restrict__ trash) {
    const int e  = blockIdx.z;
    const int m0 = blockIdx.y * BM;
    if (m0 >= counts[e]) return;
    const int n0 = blockIdx.x * BN;

    __shared__ unsigned short As0[BM * BK], As1[BM * BK];   // 8 KB each
    __shared__ unsigned short Bs0[BN * BK], Bs1[BN * BK];
    __shared__ int toks[BM];
    __shared__ unsigned long long rowp[BM];

    const int t = threadIdx.x;
    if (t < BM) {
        int tok = tlist[e * CAP + m0 + t];
        int rk  = rlist[e * CAP + m0 + t];
        toks[t] = tok;
        float* p = (rk == 0) ? out0 + (size_t)tok * HID
                 : (rk == 1) ? y1   + (size_t)tok * HID
                             : trash;
        rowp[t] = (unsigned long long)p;
    }
    __syncthreads();

    const int lane = t & 63, wave = t >> 6;
    const int rowc = lane >> 2;                     // 0..15
    const int colg = lane & 3;
    const int gcol = ((colg ^ (rowc & 3)) * 8);     // swizzled K-group (elems)

    const unsigned short* gA[2];
    const unsigned short* gB[2];
    int ldsoff[2];
    #pragma unroll
    for (int j = 0; j < 2; ++j) {
        int row = wave * 32 + j * 16 + rowc;
        gA[j] = xb + (size_t)toks[row] * DIM + gcol;
        gB[j] = Wb + ((size_t)e * HID + n0 + row) * DIM + gcol;
        ldsoff[j] = (wave * 32 + j * 16) * BK;
    }

    const int wm = wave >> 1, wn = wave & 1;
    const int r = lane & 15, quad = lane >> 4;
    const int pg = (quad ^ (r & 3)) * 8;            // physical group for frags

    f32x4 acc[4][4] = {};

    auto stage = [&](unsigned short* Ad, unsigned short* Bd, int kstep) {
        const int kc = kstep * BK;
        #pragma unroll
        for (int j = 0; j < 2; ++j) {
            async_copy16(gA[j] + kc, Ad + ldsoff[j]);
            async_copy16(gB[j] + kc, Bd + ldsoff[j]);
        }
    };
    auto compute = [&](const unsigned short* Ab, const unsigned short* Bb) {
        bf16x8 af[4], bfr[4];
        #pragma unroll
        for (int i = 0; i < 4; ++i) {
            af[i]  = *(const bf16x8*)&Ab[(wm * 64 + i * 16 + r) * BK + pg];
            bfr[i] = *(const bf16x8*)&Bb[(wn * 64 + i * 16 + r) * BK + pg];
        }
        #pragma unroll
        for (int im = 0; im < 4; ++im)
            #pragma unroll
            for (int in = 0; in < 4; ++in)
                acc[im][in] = __builtin_amdgcn_mfma_f32_16x16x32_bf16(
                    af[im], bfr[in], acc[im][in], 0, 0, 0);
    };

    stage(As0, Bs0, 0);
    __syncthreads();
    for (int k2 = 0; k2 < KITER; k2 += 2) {
        stage(As1, Bs1, k2 + 1);          // prefetch next stage
        compute(As0, Bs0);                // covers the vmcnt drain below
        __syncthreads();
        if (k2 + 2 < KITER) stage(As0, Bs0, k2 + 2);
        compute(As1, Bs1);
        __syncthreads();
    }

    // Epilogue: plain stores via per-row destination pointers.
    #pragma unroll
    for (int in = 0; in < 4; ++in) {
        int col = n0 + wn * 64 + in * 16 + r;
        #pragma unroll
        for (int im = 0; im < 4; ++im) {
            int rowb = wm * 64 + im * 16 + quad * 4;
            #pragma unroll
            for (int r4 = 0; r4 < 4; ++r4) {
                float* dst = (float*)rowp[rowb + r4];
                dst[col] = acc[im][in][r4];
            }
        }
    }
}

// ---------------------------------------------------------------------------
// out[b] = w0*(y0+bias[e0]) + w1*(y1+bias[e1]),  y0 read in-place from out.
// ---------------------------------------------------------------------------
__global__ __launch_bounds__(256) void combine_kernel(
    const float* __restrict__ y1, const float* __restrict__ eb,
    const float* __restrict__ wA, const float* __restrict__ wB,
    const int* __restrict__ eA, const int* __restrict__ eB,
    float* __restrict__ out) {
    int b = blockIdx.x;
    float w0 = wA[b], w1 = wB[b];
    int e0 = eA[b], e1 = eB[b];
    const float4* y0r = (const float4*)(out + (size_t)b * HID);
    const float4* y1r = (const float4*)(y1 + (size_t)b * HID);
    const float4* b0r = (const float4*)(eb + (size_t)e0 * HID);
    const float4* b1r = (const float4*)(eb + (size_t)e1 * HID);
    float4* o = (float4*)(out + (size_t)b * HID);
    for (int i = threadIdx.x; i < HID / 4; i += 256) {
        float4 a = y0r[i], c = y1r[i], u = b0r[i], v = b1r[i];
        float4 rs;
        rs.x = w0 * (a.x + u.x) + w1 * (c.x + v.x);
        rs.y = w0 * (a.y + u.y) + w1 * (c.y + v.y);
        rs.z = w0 * (a.z + u.z) + w1 * (c.z + v.z);
        rs.w = w0 * (a.w + u.w) + w1 * (c.w + v.w);
        o[i] = rs;
    }
}

// ---------------------------------------------------------------------------
extern "C" void kernel_launch(void* const* d_in, const int* in_sizes, int n_in,
                              void* d_out, int out_size, void* d_ws, size_t ws_size,
                              hipStream_t stream) {
    const float* x        = (const float*)d_in[0];
    const int*   labels   = (const int*)  d_in[1];
    const float* emb      = (const float*)d_in[2];
    const float* gate_W   = (const float*)d_in[3];
    const float* gate_b   = (const float*)d_in[4];
    const float* expert_W = (const float*)d_in[5];
    const float* expert_b = (const float*)d_in[6];
    float* out = (float*)d_out;

    char* ws = (char*)d_ws;
    int*   counts = (int*)ws;                                  // 32 B
    float* cbuf   = (float*)(ws + 256);                        // 96 B
    int*   tlist  = (int*)(ws + 512);                          // 135168 B
    int*   rlist  = (int*)(ws + 512 + 135168);                 // 135168 B
    float* wA     = (float*)(ws + 270848);                     // 16 KB each
    float* wB     = (float*)(ws + 287232);
    int*   eA     = (int*)  (ws + 303616);
    int*   eB     = (int*)  (ws + 320000);
    float* trash  = (float*)(ws + 336384);                     // 16 KB
    float* y1     = (float*)(ws + 352768);                     // 67 MB
    unsigned short* xb = (unsigned short*)(ws + 352768 + (size_t)B_TOK * HID * 4);
    unsigned short* Wb = xb + (size_t)B_TOK * DIM;             // 134 MB
    // total ws use ≈ 208.4 MiB

    hipMemsetAsync(counts, 0, 8 * sizeof(int), stream);

    cvt_kernel<<<(B_TOK * DIM) / (8 * 256), 256, 0, stream>>>(
        x, xb, (long)B_TOK * DIM);
    cvt_kernel<<<(NEXP * HID * DIM) / (8 * 256), 256, 0, stream>>>(
        expert_W, Wb, (long)NEXP * HID * DIM);
    compute_c_kernel<<<6, 256, 0, stream>>>(emb, gate_W, gate_b, cbuf);
    gating_kernel<<<B_TOK / 4, 256, 0, stream>>>(
        x, labels, gate_W, cbuf, counts, tlist, rlist, wA, wB, eA, eB,
        out + (size_t)B_TOK * HID);
    pad_kernel<<<NEXP, BM, 0, stream>>>(counts, tlist, rlist);
    moe_gemm_kernel<<<dim3(HID / BN, B_TOK / BM, NEXP), 256, 0, stream>>>(
        xb, Wb, counts, tlist, rlist, out, y1, trash);
    combine_kernel<<<B_TOK, 256, 0, stream>>>(
        y1, expert_b, wA, wB, eA, eB, out);
}